// Round 1
// baseline (352.663 us; speedup 1.0000x reference)
//
#include <hip/hip_runtime.h>

// z[b,c,m] = sum_d S[m,c,d] * (x[b,d,m] - mean[d,m])
// B=1024, C=64, M=512.  x:(B,C,M) f32, mean:(1,C,M), S:(M,C,C), out:(B,C,M)

namespace {
constexpr int Bb = 1024, Cc = 64, Mm = 512;
constexpr int BT = 64;           // b per block
constexpr int MT = 16;           // m per block (one per wave)
constexpr int DC = 16;           // d per chunk
constexpr int NCH = Cc / DC;     // 4 chunks
constexpr int RS = DC * MT + 4;  // 260 floats per b-row in LDS (16B-aligned, bank-spread)
constexpr int BUF = BT * RS;     // floats per buffer
constexpr size_t LDS_BYTES = 2ull * BUF * sizeof(float);  // 133,120 B

__device__ __forceinline__ void load_chunk(const float* __restrict__ x,
                                           const float* __restrict__ mean,
                                           int b_base, int m_base, int k,
                                           int tid, float4* r) {
  const int q = tid & 3;  // which float4 along m
#pragma unroll
  for (int i = 0; i < 4; ++i) {
    const int row = (tid >> 2) + (i << 8);  // 0..1023 = 16d x 64b
    const int d = row >> 6;                 // 0..15
    const int b = row & 63;
    const int gd = k * DC + d;
    const float4 xv = *reinterpret_cast<const float4*>(
        x + (((b_base + b) * Cc + gd) * Mm + m_base + q * 4));
    const float4 mv = *reinterpret_cast<const float4*>(
        mean + (gd * Mm + m_base + q * 4));
    r[i] = make_float4(xv.x - mv.x, xv.y - mv.y, xv.z - mv.z, xv.w - mv.w);
  }
}

__device__ __forceinline__ void store_chunk(float* __restrict__ xsbuf, int tid,
                                            const float4* r) {
  const int q = tid & 3;
#pragma unroll
  for (int i = 0; i < 4; ++i) {
    const int row = (tid >> 2) + (i << 8);
    const int d = row >> 6;
    const int b = row & 63;
    *reinterpret_cast<float4*>(&xsbuf[b * RS + d * MT + q * 4]) = r[i];
  }
}
}  // namespace

__global__ __launch_bounds__(1024, 4) void zca_fwd(
    const float* __restrict__ x, const float* __restrict__ mean,
    const float* __restrict__ S, float* __restrict__ out) {
  extern __shared__ float xs[];  // [2][BUF]
  const int tid = threadIdx.x;
  const int lane = tid & 63;
  const int w = __builtin_amdgcn_readfirstlane(tid >> 6);  // wave id == m_local

  // XCD-bijective swizzle: 512 blocks, 8 XCDs -> each XCD a contiguous m-range
  const int id = blockIdx.x;                  // 0..511
  const int sw = ((id & 7) << 6) + (id >> 3); // bijective
  const int mt = sw >> 4;                     // 0..31
  const int bt = sw & 15;                     // 0..15
  const int m_base = mt * MT;
  const int b_base = bt * BT;

  float acc[Cc];
#pragma unroll
  for (int c = 0; c < Cc; ++c) acc[c] = 0.f;

  const float* Sm = S + (size_t)(m_base + w) * (Cc * Cc);  // wave-uniform

  // --- prologue: stage chunk 0, issue loads for chunk 1 ---
  float4 st[4];
  load_chunk(x, mean, b_base, m_base, 0, tid, st);
  store_chunk(&xs[0], tid, st);
  load_chunk(x, mean, b_base, m_base, 1, tid, st);
  __syncthreads();

  // --- main loop: 1 barrier per chunk, double-buffered ---
  for (int k = 0; k < NCH; ++k) {
    if (k < NCH - 1) {
      store_chunk(&xs[((k + 1) & 1) * BUF], tid, st);  // write chunk k+1
      if (k < NCH - 2) load_chunk(x, mean, b_base, m_base, k + 2, tid, st);
    }
    const float* buf = &xs[(k & 1) * BUF];
    float xv[DC];
#pragma unroll
    for (int j = 0; j < DC; ++j) xv[j] = buf[lane * RS + j * MT + w];
    const float* Sk = Sm + k * DC;
#pragma unroll
    for (int c = 0; c < Cc; ++c) {
      float a = acc[c];
#pragma unroll
      for (int j = 0; j < DC; ++j) a = fmaf(Sk[c * Cc + j], xv[j], a);
      acc[c] = a;
    }
    if (k < NCH - 1) __syncthreads();
  }

  // --- epilogue: transpose z through LDS for m-contiguous float4 stores ---
  const int q = tid & 3;
  for (int cc = 0; cc < 4; ++cc) {
    float* zt = &xs[(cc & 1) * BUF];
#pragma unroll
    for (int ci = 0; ci < 16; ++ci)
      zt[lane * RS + ci * MT + w] = acc[cc * 16 + ci];
    __syncthreads();
#pragma unroll
    for (int i = 0; i < 4; ++i) {
      const int row = (tid >> 2) + (i << 8);  // 64b x 16c rows
      const int b = row >> 4;
      const int cl = row & 15;
      const float4 v =
          *reinterpret_cast<const float4*>(&zt[b * RS + cl * MT + q * 4]);
      *reinterpret_cast<float4*>(
          &out[((b_base + b) * Cc + cc * 16 + cl) * Mm + m_base + q * 4]) = v;
    }
  }
}

extern "C" void kernel_launch(void* const* d_in, const int* in_sizes, int n_in,
                              void* d_out, int out_size, void* d_ws,
                              size_t ws_size, hipStream_t stream) {
  const float* x = (const float*)d_in[0];
  const float* mean = (const float*)d_in[1];
  const float* S = (const float*)d_in[2];
  float* out = (float*)d_out;
  const int nblocks = (Bb / BT) * (Mm / MT);  // 16 * 32 = 512
  hipLaunchKernelGGL(zca_fwd, dim3(nblocks), dim3(1024), LDS_BYTES, stream, x,
                     mean, S, out);
}